// Round 6
// baseline (188.050 us; speedup 1.0000x reference)
//
#include <hip/hip_runtime.h>
#include <math.h>

// ---------- types ----------
typedef __attribute__((ext_vector_type(8))) short bf16x8;   // 8 x bf16
typedef __attribute__((ext_vector_type(4))) float f32x4;

#define AS1(p) ((__attribute__((address_space(1))) void*)(uintptr_t)(p))
#define AS3(p) ((__attribute__((address_space(3))) void*)(p))

static __device__ __forceinline__ unsigned short f2bf(float f) {
    unsigned int u = __float_as_uint(f);
    unsigned int r = (u + 0x7fffu + ((u >> 16) & 1u)) >> 16;   // RNE
    return (unsigned short)r;
}

// ---------- sizes ----------
#define NPATCH 8191
#define NTOK   8192          // with cls row 0
#define INDIM  1024
#define EMBED  512

// ============================================================
// 1) k_pre:  blocks 0..7      q0 = cls@Wq+bq (coalesced) ; inits
//            blocks 8..519    W1 -> w1t [N][K] bf16 transpose
//            blocks 520..2567 x (f32) -> xb (bf16), row 8191 zeroed
//    (stragglers dispatched FIRST so they overlap the convert)
// ============================================================
__global__ void k_pre(const float* __restrict__ x, unsigned short* __restrict__ xb,
                      const float* __restrict__ W1, unsigned short* __restrict__ w1t,
                      const float* __restrict__ cls, const float* __restrict__ Wq,
                      const float* __restrict__ bq, const float* __restrict__ bv,
                      const float* __restrict__ bo,
                      float* __restrict__ q0, float* __restrict__ h_full,
                      float* __restrict__ svec, float* __restrict__ attn0,
                      float* __restrict__ r0, float* __restrict__ scores) {
    const int b = blockIdx.x;
    const int t = threadIdx.x;
    if (b < 8) {
        // ---- q0: block b owns d in [b*64, b*64+64); wave c does rows in%4==c
        __shared__ float part[4][64];
        const int c  = t >> 6;             // 0..3
        const int dl = t & 63;
        const int d  = b * 64 + dl;
        float acc = 0.f;
        for (int in = c; in < EMBED; in += 4)
            acc = fmaf(cls[in], Wq[(size_t)in * EMBED + d], acc);   // 256B/wave/row, coalesced
        part[c][dl] = acc;
        __syncthreads();
        if (c == 0) {
            const float s = part[0][dl] + part[1][dl] + part[2][dl] + part[3][dl];
            q0[d]     = s + bq[d];
            h_full[d] = cls[d];
            svec[d]   = 0.f;
            attn0[d]  = bv[d];             // bias pre-seeded for atomic accumulation
            r0[d]     = cls[d] + bo[d];    // residual + bias pre-seeded
            #pragma unroll
            for (int i = 0; i < 16; ++i) scores[d * 16 + i] = 0.f;
        }
    } else if (b < 520) {
        __shared__ float tile[32][33];
        const int bb = b - 8;
        const int bk = bb >> 4;              // 0..31 (K tiles)
        const int bn = bb & 15;              // 0..15 (N tiles)
        const int r  = t >> 3;               // 0..31
        const int c4 = (t & 7) * 4;          // 0,4,..,28
        float4 v = *(const float4*)(W1 + (size_t)(bk * 32 + r) * EMBED + bn * 32 + c4);
        tile[r][c4 + 0] = v.x; tile[r][c4 + 1] = v.y; tile[r][c4 + 2] = v.z; tile[r][c4 + 3] = v.w;
        __syncthreads();
        ushort4 o;
        o.x = f2bf(tile[c4 + 0][r]); o.y = f2bf(tile[c4 + 1][r]);
        o.z = f2bf(tile[c4 + 2][r]); o.w = f2bf(tile[c4 + 3][r]);
        *(ushort4*)(w1t + (size_t)(bn * 32 + r) * INDIM + bk * 32 + c4) = o;
    } else {
        const int cb = b - 520;              // 0..2047
        const int NV = NPATCH * INDIM / 4;   // valid float4s
        const int NT = NTOK   * INDIM / 4;
        for (int i = cb * 256 + t; i < NT; i += 2048 * 256) {
            ushort4 o;
            if (i < NV) {
                float4 v = ((const float4*)x)[i];
                o.x = f2bf(v.x); o.y = f2bf(v.y); o.z = f2bf(v.z); o.w = f2bf(v.w);
            } else {
                o.x = 0; o.y = 0; o.z = 0; o.w = 0;
            }
            ((ushort4*)xb)[i] = o;
        }
    }
}

// ============================================================
// 2) u[in] = Wk[in,:] . q0   (so scores = h . u)  grid 32 x 256
// ============================================================
__global__ void k_u(const float* __restrict__ Wk, const float* __restrict__ q0,
                    float* __restrict__ u) {
    const int wave = blockIdx.x * 4 + (threadIdx.x >> 6);  // 0..127
    const int lane = threadIdx.x & 63;
    const float4* q4 = (const float4*)q0;
    float4 qa = q4[lane * 2], qb = q4[lane * 2 + 1];
    for (int rr = 0; rr < 4; ++rr) {
        const int row = wave * 4 + rr;                     // 0..511
        const float4* wr = (const float4*)(Wk + (size_t)row * EMBED);
        float4 a = wr[lane * 2], b = wr[lane * 2 + 1];
        float acc = a.x*qa.x + a.y*qa.y + a.z*qa.z + a.w*qa.w
                  + b.x*qb.x + b.y*qb.y + b.z*qb.z + b.w*qb.w;
        for (int off = 32; off; off >>= 1) acc += __shfl_down(acc, off);
        if (lane == 0) u[row] = acc;
    }
}

// ============================================================
// 3) GEMM: h_full[1+a][n] = relu( xb[a,:] @ w1t[n,:]^T + b1[n] )
//    + fused scores[1+a] = h_row . u
//    128x128 tile, BK=128, dbuf LDS (128KB), grid 256 (1 blk/CU)
//    Both operands via global_load_lds w=16, pre-swizzled source,
//    XOR-swizzled ds_read_b128 (conflict-free). 8-iter K chain.
//    Block map: rg = (bid&7)|((bid>>5)<<3), cg = (bid>>3)&3 ->
//    4 cg-siblings of each rg land on one XCD (A panel L2-resident).
// ============================================================
__global__ __launch_bounds__(256) void k_gemm(const unsigned short* __restrict__ xb,
                                              const unsigned short* __restrict__ w1t,
                                              const float* __restrict__ b1,
                                              const float* __restrict__ u,
                                              float* __restrict__ h_full,
                                              float* __restrict__ scores) {
    __shared__ __align__(16) unsigned short As[2][128 * 128];   // 32 KB x2
    __shared__ __align__(16) unsigned short Bs[2][128 * 128];   // 32 KB x2
    const int tid  = threadIdx.x;
    const int wave = tid >> 6;
    const int lane = tid & 63;
    const int bid  = blockIdx.x;
    const int rg   = (bid & 7) | ((bid >> 5) << 3);   // 0..63
    const int cg   = (bid >> 3) & 3;                  // 0..3
    const int wr   = wave >> 1, wc = wave & 1;
    const int fr   = lane & 15, fq = lane >> 4;

    // ---- staging: 2048 16B-chunks per operand per tile; 8 issues/thread.
    // chunk c = (i*4+wave)*64 + lane: row = c>>4 (0..127), koct = c&15.
    // LDS linear dst = c*16B  ==  [row][koct] row-major.
    // Global source pre-swizzled: koct_g = koct ^ (row&7)  (involution).
    size_t srcA[8], srcB[8];
    int dstc[8];
    #pragma unroll
    for (int i = 0; i < 8; ++i) {
        const int c0  = (i * 4 + wave) * 64;          // wave-uniform
        const int c   = c0 + lane;
        const int row = c >> 4, koct = c & 15;
        const int kg  = koct ^ (row & 7);
        dstc[i] = c0 * 8;                             // shorts
        srcA[i] = (size_t)(rg * 128 + row) * INDIM + kg * 8;
        srcB[i] = (size_t)(cg * 128 + row) * INDIM + kg * 8;
    }

    f32x4 acc[4][4] = {};

    // fragment read offsets (shorts): row*128 + ((fq^(row&7))*8), kk adds ^ (kk*32)
    int aoff[4], boff[4];
    #pragma unroll
    for (int mi = 0; mi < 4; ++mi) {
        const int row = wr * 64 + mi * 16 + fr;
        aoff[mi] = row * 128 + ((fq ^ (row & 7)) * 8);
        const int col = wc * 64 + mi * 16 + fr;
        boff[mi] = col * 128 + ((fq ^ (col & 7)) * 8);
    }

#define STAGE(buf, k0) do { \
    _Pragma("unroll") \
    for (int i = 0; i < 8; ++i) \
        __builtin_amdgcn_global_load_lds(AS1(xb + srcA[i] + (k0)), \
                                         AS3(&As[buf][dstc[i]]), 16, 0, 0); \
    _Pragma("unroll") \
    for (int i = 0; i < 8; ++i) \
        __builtin_amdgcn_global_load_lds(AS1(w1t + srcB[i] + (k0)), \
                                         AS3(&Bs[buf][dstc[i]]), 16, 0, 0); \
    } while (0)

    STAGE(0, 0);
    __syncthreads();

    int cur = 0;
    for (int kt = 0; kt < 8; ++kt) {
        if (kt < 7) STAGE(cur ^ 1, (kt + 1) * 128);   // prefetch overlaps compute
        #pragma unroll
        for (int kk = 0; kk < 4; ++kk) {
            bf16x8 af[4], bf[4];
            #pragma unroll
            for (int mi = 0; mi < 4; ++mi)
                af[mi] = *(const bf16x8*)&As[cur][aoff[mi] ^ (kk * 32)];
            #pragma unroll
            for (int ni = 0; ni < 4; ++ni)
                bf[ni] = *(const bf16x8*)&Bs[cur][boff[ni] ^ (kk * 32)];
            #pragma unroll
            for (int mi = 0; mi < 4; ++mi)
                #pragma unroll
                for (int ni = 0; ni < 4; ++ni)
                    acc[mi][ni] = __builtin_amdgcn_mfma_f32_16x16x32_bf16(af[mi], bf[ni], acc[mi][ni], 0, 0, 0);
        }
        __syncthreads();                              // drains prefetch + ds reads
        cur ^= 1;
    }
#undef STAGE

    // epilogue: a = rg*128 + wr*64 + mi*16 + fq*4 + rr ; col = cg*128 + wc*64 + ni*16 + fr
    float uv[4], bvv[4];
    #pragma unroll
    for (int ni = 0; ni < 4; ++ni) {
        const int col = cg * 128 + wc * 64 + ni * 16 + fr;
        uv[ni]  = u[col];
        bvv[ni] = b1[col];
    }
    #pragma unroll
    for (int mi = 0; mi < 4; ++mi) {
        #pragma unroll
        for (int rr = 0; rr < 4; ++rr) {
            const int a = rg * 128 + wr * 64 + mi * 16 + fq * 4 + rr;
            if (a < NPATCH) {
                float sc = 0.f;
                #pragma unroll
                for (int ni = 0; ni < 4; ++ni) {
                    const int col = cg * 128 + wc * 64 + ni * 16 + fr;
                    float v = fmaxf(acc[mi][ni][rr] + bvv[ni], 0.f);
                    h_full[(size_t)(a + 1) * EMBED + col] = v;
                    sc = fmaf(v, uv[ni], sc);
                }
                sc += __shfl_xor(sc, 1);
                sc += __shfl_xor(sc, 2);
                sc += __shfl_xor(sc, 4);
                sc += __shfl_xor(sc, 8);
                if (fr == 0) atomicAdd(&scores[a + 1], sc);
            }
        }
    }
}

// ============================================================
// 4) chunk softmax (16 x 512) then full softmax -> wts[8192]
//    1 block x 1024 threads; wave == chunk. Also computes scores[0].
// ============================================================
__global__ void k_softmax(const float* __restrict__ scores, const float* __restrict__ h_full,
                          const float* __restrict__ u, float* __restrict__ wts) {
    __shared__ float redA[16], redB[16];
    __shared__ float s0sh;
    const int t = threadIdx.x, wv = t >> 6, lane = t & 63;
    const float rs = 0.04419417382415922f;   // 1/sqrt(512)

    if (wv == 0) {   // score for cls row (row 0 of h_full)
        const float4* hr = (const float4*)h_full;
        const float4* u4 = (const float4*)u;
        float4 a = hr[lane * 2], b = hr[lane * 2 + 1];
        float4 qa = u4[lane * 2], qb = u4[lane * 2 + 1];
        float acc = a.x*qa.x + a.y*qa.y + a.z*qa.z + a.w*qa.w
                  + b.x*qb.x + b.y*qb.y + b.z*qb.z + b.w*qb.w;
        for (int off = 32; off; off >>= 1) acc += __shfl_down(acc, off);
        if (lane == 0) s0sh = acc * rs;
    }
    __syncthreads();

    const float4* s4 = (const float4*)scores;
    float4 a = s4[2 * t], b = s4[2 * t + 1];
    float v[8] = {a.x*rs, a.y*rs, a.z*rs, a.w*rs, b.x*rs, b.y*rs, b.z*rs, b.w*rs};
    if (t == 0) v[0] = s0sh;

    // per-chunk softmax (one wave == one 512-chunk)
    float mx = v[0];
    #pragma unroll
    for (int j = 1; j < 8; ++j) mx = fmaxf(mx, v[j]);
    for (int off = 32; off; off >>= 1) mx = fmaxf(mx, __shfl_xor(mx, off));
    float sm = 0.f;
    #pragma unroll
    for (int j = 0; j < 8; ++j) { v[j] = expf(v[j] - mx); sm += v[j]; }
    for (int off = 32; off; off >>= 1) sm += __shfl_xor(sm, off);
    float inv = 1.f / sm;
    #pragma unroll
    for (int j = 0; j < 8; ++j) v[j] *= inv;

    // full softmax over all 8192
    float m2 = v[0];
    #pragma unroll
    for (int j = 1; j < 8; ++j) m2 = fmaxf(m2, v[j]);
    for (int off = 32; off; off >>= 1) m2 = fmaxf(m2, __shfl_xor(m2, off));
    if (lane == 0) redA[wv] = m2;
    __syncthreads();
    float gm = redA[0];
    for (int i = 1; i < 16; ++i) gm = fmaxf(gm, redA[i]);
    float s2 = 0.f;
    #pragma unroll
    for (int j = 0; j < 8; ++j) { v[j] = expf(v[j] - gm); s2 += v[j]; }
    for (int off = 32; off; off >>= 1) s2 += __shfl_xor(s2, off);
    if (lane == 0) redB[wv] = s2;
    __syncthreads();
    float gs = 0.f;
    for (int i = 0; i < 16; ++i) gs += redB[i];
    float gi = 1.f / gs;
    float4 o1 = {v[0] * gi, v[1] * gi, v[2] * gi, v[3] * gi};
    float4 o2 = {v[4] * gi, v[5] * gi, v[6] * gi, v[7] * gi};
    float4* w4 = (float4*)wts;
    w4[2 * t] = o1; w4[2 * t + 1] = o2;
}

// ============================================================
// 5) svec[d] = sum_j wts[j] * h_full[j][d]   grid 256 x 256
// ============================================================
__global__ void k_wsum(const float* __restrict__ h_full, const float* __restrict__ wts,
                       float* __restrict__ svec) {
    const int b = blockIdx.x, t = threadIdx.x;
    float a0 = 0.f, a1 = 0.f;
    const int j0 = b * 32;
    for (int j = j0; j < j0 + 32; ++j) {
        const float wj = wts[j];
        const float* hr = h_full + (size_t)j * EMBED;
        a0 = fmaf(wj, hr[t], a0);
        a1 = fmaf(wj, hr[t + 256], a1);
    }
    atomicAdd(&svec[t], a0);
    atomicAdd(&svec[t + 256], a1);
}

// ============================================================
// 6) attn0 += svec @ Wv  (attn0 pre-seeded with bv)  grid 32 x 256
// ============================================================
__global__ void k_attn0(const float* __restrict__ svec, const float* __restrict__ Wv,
                        float* __restrict__ attn0) {
    const int b = blockIdx.x, t = threadIdx.x;
    float a0 = 0.f, a1 = 0.f;
    const int e0 = b * 16;
    for (int e = e0; e < e0 + 16; ++e) {
        const float s = svec[e];
        const float* wr = Wv + (size_t)e * EMBED;
        a0 = fmaf(s, wr[t], a0);
        a1 = fmaf(s, wr[t + 256], a1);
    }
    atomicAdd(&attn0[t], a0);
    atomicAdd(&attn0[t + 256], a1);
}

// ============================================================
// 7) r0 += attn0 @ Wo  (r0 pre-seeded with cls+bo)  grid 32 x 256
// ============================================================
__global__ void k_r0(const float* __restrict__ attn0, const float* __restrict__ Wo,
                     float* __restrict__ r0) {
    const int b = blockIdx.x, t = threadIdx.x;
    float a0 = 0.f, a1 = 0.f;
    const int e0 = b * 16;
    for (int e = e0; e < e0 + 16; ++e) {
        const float s = attn0[e];
        const float* wr = Wo + (size_t)e * EMBED;
        a0 = fmaf(s, wr[t], a0);
        a1 = fmaf(s, wr[t + 256], a1);
    }
    atomicAdd(&r0[t], a0);
    atomicAdd(&r0[t + 256], a1);
}

// ============================================================
// 8) LayerNorm(r0) -> logits = hn @ Wc + bc    1 block x 512
// ============================================================
__global__ void k_final(const float* __restrict__ r0, const float* __restrict__ ln_g,
                        const float* __restrict__ ln_b, const float* __restrict__ Wc,
                        const float* __restrict__ bc, float* __restrict__ out) {
    __shared__ float red[8];
    const int t = threadIdx.x, wv = t >> 6, lane = t & 63;
    const float x = r0[t];

    float sm = x;
    for (int off = 32; off; off >>= 1) sm += __shfl_down(sm, off);
    if (lane == 0) red[wv] = sm;
    __syncthreads();
    float mu = 0.f;
    for (int i = 0; i < 8; ++i) mu += red[i];
    mu *= (1.f / 512.f);
    const float dx = x - mu;

    __syncthreads();
    float q = dx * dx;
    for (int off = 32; off; off >>= 1) q += __shfl_down(q, off);
    if (lane == 0) red[wv] = q;
    __syncthreads();
    float var = 0.f;
    for (int i = 0; i < 8; ++i) var += red[i];
    var *= (1.f / 512.f);

    const float hn = dx / sqrtf(var + 1e-5f) * ln_g[t] + ln_b[t];
    float p0 = hn * Wc[2 * t];
    float p1 = hn * Wc[2 * t + 1];

    __syncthreads();
    for (int off = 32; off; off >>= 1) p0 += __shfl_down(p0, off);
    if (lane == 0) red[wv] = p0;
    __syncthreads();
    if (t == 0) {
        float tot = 0.f;
        for (int i = 0; i < 8; ++i) tot += red[i];
        out[0] = tot + bc[0];
    }
    __syncthreads();
    for (int off = 32; off; off >>= 1) p1 += __shfl_down(p1, off);
    if (lane == 0) red[wv] = p1;
    __syncthreads();
    if (t == 0) {
        float tot = 0.f;
        for (int i = 0; i < 8; ++i) tot += red[i];
        out[1] = tot + bc[1];
    }
}

// ============================================================
extern "C" void kernel_launch(void* const* d_in, const int* in_sizes, int n_in,
                              void* d_out, int out_size, void* d_ws, size_t ws_size,
                              hipStream_t stream) {
    const float* x    = (const float*)d_in[0];
    const float* W1   = (const float*)d_in[1];
    const float* b1   = (const float*)d_in[2];
    const float* cls  = (const float*)d_in[3];
    const float* Wq   = (const float*)d_in[4];
    const float* bq   = (const float*)d_in[5];
    const float* Wk   = (const float*)d_in[6];
    const float* bk   = (const float*)d_in[7];   (void)bk;  // uniform shift cancels in softmax
    const float* Wv   = (const float*)d_in[8];
    const float* bv   = (const float*)d_in[9];
    const float* Wo   = (const float*)d_in[10];
    const float* bo   = (const float*)d_in[11];
    const float* ln_g = (const float*)d_in[12];
    const float* ln_b = (const float*)d_in[13];
    const float* Wc   = (const float*)d_in[14];
    const float* bc   = (const float*)d_in[15];
    float* out = (float*)d_out;

    char* ws = (char*)d_ws;
    unsigned short* xb     = (unsigned short*)(ws);                    // 16 MB
    unsigned short* w1t    = (unsigned short*)(ws + 16777216);         // 1 MB
    float*          h_full = (float*)(ws + 17825792);                  // 16 MB
    float*          scores = (float*)(ws + 34603008);                  // 32 KB
    float*          wts    = (float*)(ws + 34635776);                  // 32 KB
    float*          q0     = (float*)(ws + 34668544);
    float*          u      = (float*)(ws + 34670592);
    float*          svec   = (float*)(ws + 34672640);
    float*          attn0  = (float*)(ws + 34674688);
    float*          r0     = (float*)(ws + 34676736);

    k_pre     <<<2568, 256, 0, stream>>>(x, xb, W1, w1t, cls, Wq, bq, bv, bo,
                                         q0, h_full, svec, attn0, r0, scores);
    k_u       <<<32,  256, 0, stream>>>(Wk, q0, u);
    k_gemm    <<<256, 256, 0, stream>>>(xb, w1t, b1, u, h_full, scores);
    k_softmax <<<1,  1024, 0, stream>>>(scores, h_full, u, wts);
    k_wsum    <<<256, 256, 0, stream>>>(h_full, wts, svec);
    k_attn0   <<<32,  256, 0, stream>>>(svec, Wv, attn0);
    k_r0      <<<32,  256, 0, stream>>>(attn0, Wo, r0);
    k_final   <<<1,   512, 0, stream>>>(r0, ln_g, ln_b, Wc, bc, out);
}

// Round 7
// 185.090 us; speedup vs baseline: 1.0160x; 1.0160x over previous
//
#include <hip/hip_runtime.h>
#include <math.h>

// ---------- types ----------
typedef __attribute__((ext_vector_type(8))) short bf16x8;   // 8 x bf16
typedef __attribute__((ext_vector_type(4))) float f32x4;

#define AS1(p) ((__attribute__((address_space(1))) void*)(uintptr_t)(p))
#define AS3(p) ((__attribute__((address_space(3))) void*)(p))

static __device__ __forceinline__ unsigned short f2bf(float f) {
    unsigned int u = __float_as_uint(f);
    unsigned int r = (u + 0x7fffu + ((u >> 16) & 1u)) >> 16;   // RNE
    return (unsigned short)r;
}

// ---------- sizes ----------
#define NPATCH 8191
#define NTOK   8192          // with cls row 0
#define INDIM  1024
#define EMBED  512

// ============================================================
// 1) k_pre:  blocks 0..7       q0 = cls@Wq+bq (coalesced) ; inits
//            blocks 8..1031    x (f32) -> xb (bf16), 8x MLP unroll
//            blocks 1032..1543 W1 -> w1t [N][K] bf16 transpose
// ============================================================
__global__ void k_pre(const float* __restrict__ x, unsigned short* __restrict__ xb,
                      const float* __restrict__ W1, unsigned short* __restrict__ w1t,
                      const float* __restrict__ cls, const float* __restrict__ Wq,
                      const float* __restrict__ bq, const float* __restrict__ bv,
                      const float* __restrict__ bo,
                      float* __restrict__ q0, float* __restrict__ h_full,
                      float* __restrict__ svec, float* __restrict__ attn0,
                      float* __restrict__ r0, float* __restrict__ scores) {
    const int b = blockIdx.x;
    const int t = threadIdx.x;
    if (b < 8) {
        // ---- q0: block b owns d in [b*64, b*64+64); wave c does rows in%4==c
        __shared__ float part[4][64];
        const int c  = t >> 6;             // 0..3
        const int dl = t & 63;
        const int d  = b * 64 + dl;
        float acc = 0.f;
        for (int in = c; in < EMBED; in += 4)
            acc = fmaf(cls[in], Wq[(size_t)in * EMBED + d], acc);   // coalesced 256B/wave/row
        part[c][dl] = acc;
        __syncthreads();
        if (c == 0) {
            const float s = part[0][dl] + part[1][dl] + part[2][dl] + part[3][dl];
            q0[d]     = s + bq[d];
            h_full[d] = cls[d];
            svec[d]   = 0.f;
            attn0[d]  = bv[d];             // bias pre-seeded for atomic accumulation
            r0[d]     = cls[d] + bo[d];    // residual + bias pre-seeded
            #pragma unroll
            for (int i = 0; i < 16; ++i) scores[d * 16 + i] = 0.f;
        }
    } else if (b < 1032) {
        // ---- convert: 8 independent float4 loads per thread (MLP), then stores
        const int cb   = b - 8;                    // 0..1023
        const int base = cb * 2048 + t;            // float4 index
        const int NV   = NPATCH * INDIM / 4;       // 2,096,896 valid float4s
        const float4* x4 = (const float4*)x;
        ushort4* xb4 = (ushort4*)xb;
        float4 vv[8];
        #pragma unroll
        for (int k = 0; k < 8; ++k) {
            const int i = base + k * 256;
            if (i < NV) vv[k] = x4[i];
            else        vv[k] = make_float4(0.f, 0.f, 0.f, 0.f);
        }
        #pragma unroll
        for (int k = 0; k < 8; ++k) {
            ushort4 o;
            o.x = f2bf(vv[k].x); o.y = f2bf(vv[k].y);
            o.z = f2bf(vv[k].z); o.w = f2bf(vv[k].w);
            xb4[base + k * 256] = o;
        }
    } else {
        __shared__ float tile[32][33];
        const int bb = b - 1032;
        const int bk = bb >> 4;              // 0..31 (K tiles)
        const int bn = bb & 15;              // 0..15 (N tiles)
        const int r  = t >> 3;               // 0..31
        const int c4 = (t & 7) * 4;          // 0,4,..,28
        float4 v = *(const float4*)(W1 + (size_t)(bk * 32 + r) * EMBED + bn * 32 + c4);
        tile[r][c4 + 0] = v.x; tile[r][c4 + 1] = v.y; tile[r][c4 + 2] = v.z; tile[r][c4 + 3] = v.w;
        __syncthreads();
        ushort4 o;
        o.x = f2bf(tile[c4 + 0][r]); o.y = f2bf(tile[c4 + 1][r]);
        o.z = f2bf(tile[c4 + 2][r]); o.w = f2bf(tile[c4 + 3][r]);
        *(ushort4*)(w1t + (size_t)(bn * 32 + r) * INDIM + bk * 32 + c4) = o;
    }
}

// ============================================================
// 2) u[in] = Wk[in,:] . q0   (so scores = h . u)  grid 32 x 256
// ============================================================
__global__ void k_u(const float* __restrict__ Wk, const float* __restrict__ q0,
                    float* __restrict__ u) {
    const int wave = blockIdx.x * 4 + (threadIdx.x >> 6);  // 0..127
    const int lane = threadIdx.x & 63;
    const float4* q4 = (const float4*)q0;
    float4 qa = q4[lane * 2], qb = q4[lane * 2 + 1];
    for (int rr = 0; rr < 4; ++rr) {
        const int row = wave * 4 + rr;                     // 0..511
        const float4* wr = (const float4*)(Wk + (size_t)row * EMBED);
        float4 a = wr[lane * 2], b = wr[lane * 2 + 1];
        float acc = a.x*qa.x + a.y*qa.y + a.z*qa.z + a.w*qa.w
                  + b.x*qb.x + b.y*qb.y + b.z*qb.z + b.w*qb.w;
        for (int off = 32; off; off >>= 1) acc += __shfl_down(acc, off);
        if (lane == 0) u[row] = acc;
    }
}

// ============================================================
// 3) GEMM: h_full[1+a][n] = relu( xb[a,:] @ w1t[n,:]^T + b1[n] )
//    + fused scores[1+a] = h_row . u  (raw dot, scaled later)
//    128x128 tile, BK=128, dbuf LDS (128KB), grid 256 (1 blk/CU)
//    Both operands via global_load_lds w=16, pre-swizzled source,
//    XOR-swizzled ds_read_b128 (conflict-free). 8-iter K chain.
//    Block map: rg = (bid&7)|((bid>>5)<<3), cg = (bid>>3)&3 ->
//    4 cg-siblings of each rg land on one XCD (A panel L2-resident).
// ============================================================
__global__ __launch_bounds__(256) void k_gemm(const unsigned short* __restrict__ xb,
                                              const unsigned short* __restrict__ w1t,
                                              const float* __restrict__ b1,
                                              const float* __restrict__ u,
                                              float* __restrict__ h_full,
                                              float* __restrict__ scores) {
    __shared__ __align__(16) unsigned short As[2][128 * 128];   // 32 KB x2
    __shared__ __align__(16) unsigned short Bs[2][128 * 128];   // 32 KB x2
    const int tid  = threadIdx.x;
    const int wave = tid >> 6;
    const int lane = tid & 63;
    const int bid  = blockIdx.x;
    const int rg   = (bid & 7) | ((bid >> 5) << 3);   // 0..63
    const int cg   = (bid >> 3) & 3;                  // 0..3
    const int wr   = wave >> 1, wc = wave & 1;
    const int fr   = lane & 15, fq = lane >> 4;

    // staging: chunk c = (i*4+wave)*64 + lane: row = c>>4, koct = c&15.
    // LDS linear dst = c*16B; global source pre-swizzled koct^(row&7).
    size_t srcA[8], srcB[8];
    int dstc[8];
    #pragma unroll
    for (int i = 0; i < 8; ++i) {
        const int c0  = (i * 4 + wave) * 64;          // wave-uniform
        const int c   = c0 + lane;
        const int row = c >> 4, koct = c & 15;
        const int kg  = koct ^ (row & 7);
        dstc[i] = c0 * 8;                             // shorts
        srcA[i] = (size_t)(rg * 128 + row) * INDIM + kg * 8;
        srcB[i] = (size_t)(cg * 128 + row) * INDIM + kg * 8;
    }

    f32x4 acc[4][4] = {};

    int aoff[4], boff[4];
    #pragma unroll
    for (int mi = 0; mi < 4; ++mi) {
        const int row = wr * 64 + mi * 16 + fr;
        aoff[mi] = row * 128 + ((fq ^ (row & 7)) * 8);
        const int col = wc * 64 + mi * 16 + fr;
        boff[mi] = col * 128 + ((fq ^ (col & 7)) * 8);
    }

#define STAGE(buf, k0) do { \
    _Pragma("unroll") \
    for (int i = 0; i < 8; ++i) \
        __builtin_amdgcn_global_load_lds(AS1(xb + srcA[i] + (k0)), \
                                         AS3(&As[buf][dstc[i]]), 16, 0, 0); \
    _Pragma("unroll") \
    for (int i = 0; i < 8; ++i) \
        __builtin_amdgcn_global_load_lds(AS1(w1t + srcB[i] + (k0)), \
                                         AS3(&Bs[buf][dstc[i]]), 16, 0, 0); \
    } while (0)

    STAGE(0, 0);
    __syncthreads();

    int cur = 0;
    for (int kt = 0; kt < 8; ++kt) {
        if (kt < 7) STAGE(cur ^ 1, (kt + 1) * 128);   // prefetch overlaps compute
        #pragma unroll
        for (int kk = 0; kk < 4; ++kk) {
            bf16x8 af[4], bf[4];
            #pragma unroll
            for (int mi = 0; mi < 4; ++mi)
                af[mi] = *(const bf16x8*)&As[cur][aoff[mi] ^ (kk * 32)];
            #pragma unroll
            for (int ni = 0; ni < 4; ++ni)
                bf[ni] = *(const bf16x8*)&Bs[cur][boff[ni] ^ (kk * 32)];
            #pragma unroll
            for (int mi = 0; mi < 4; ++mi)
                #pragma unroll
                for (int ni = 0; ni < 4; ++ni)
                    acc[mi][ni] = __builtin_amdgcn_mfma_f32_16x16x32_bf16(af[mi], bf[ni], acc[mi][ni], 0, 0, 0);
        }
        __syncthreads();
        cur ^= 1;
    }
#undef STAGE

    float uv[4], bvv[4];
    #pragma unroll
    for (int ni = 0; ni < 4; ++ni) {
        const int col = cg * 128 + wc * 64 + ni * 16 + fr;
        uv[ni]  = u[col];
        bvv[ni] = b1[col];
    }
    #pragma unroll
    for (int mi = 0; mi < 4; ++mi) {
        #pragma unroll
        for (int rr = 0; rr < 4; ++rr) {
            const int a = rg * 128 + wr * 64 + mi * 16 + fq * 4 + rr;
            if (a < NPATCH) {
                float sc = 0.f;
                #pragma unroll
                for (int ni = 0; ni < 4; ++ni) {
                    const int col = cg * 128 + wc * 64 + ni * 16 + fr;
                    float v = fmaxf(acc[mi][ni][rr] + bvv[ni], 0.f);
                    h_full[(size_t)(a + 1) * EMBED + col] = v;
                    sc = fmaf(v, uv[ni], sc);
                }
                sc += __shfl_xor(sc, 1);
                sc += __shfl_xor(sc, 2);
                sc += __shfl_xor(sc, 4);
                sc += __shfl_xor(sc, 8);
                if (fr == 0) atomicAdd(&scores[a + 1], sc);
            }
        }
    }
}

// ============================================================
// 4) FUSED softmax + wsum.  grid 256 x 256.
//    Each block redundantly computes the full two-stage softmax
//    (thread t owns scores[32t..32t+32); chunk = 16-lane group),
//    then does the weighted h-row sum for its own 32 rows
//    j in [b*32, b*32+32)  (held by thread t == b).
// ============================================================
__global__ void k_wsum(const float* __restrict__ scores, const float* __restrict__ h_full,
                       const float* __restrict__ u, const float* __restrict__ cls,
                       float* __restrict__ svec) {
    __shared__ float redf[4];
    __shared__ float wloc[32];
    const int b = blockIdx.x, t = threadIdx.x;
    const int wv = t >> 6, lane = t & 63;
    const float rs = 0.04419417382415922f;   // 1/sqrt(512)

    // ---- s0 = (cls . u) * rs
    float part = cls[t] * u[t] + cls[t + 256] * u[t + 256];
    for (int off = 32; off; off >>= 1) part += __shfl_down(part, off);
    if (lane == 0) redf[wv] = part;
    __syncthreads();
    const float s0 = (redf[0] + redf[1] + redf[2] + redf[3]) * rs;
    __syncthreads();   // all reads of redf done before reuse

    // ---- load 32 scores (thread t owns j in [32t, 32t+32))
    float v[32];
    const float4* s4 = (const float4*)(scores + t * 32);
    #pragma unroll
    for (int q = 0; q < 8; ++q) {
        float4 a = s4[q];
        v[q*4+0] = a.x*rs; v[q*4+1] = a.y*rs; v[q*4+2] = a.z*rs; v[q*4+3] = a.w*rs;
    }
    if (t == 0) v[0] = s0;

    // ---- chunk softmax: chunk = 16-lane group (512 scores)
    float mx = v[0];
    #pragma unroll
    for (int j = 1; j < 32; ++j) mx = fmaxf(mx, v[j]);
    mx = fmaxf(mx, __shfl_xor(mx, 1));
    mx = fmaxf(mx, __shfl_xor(mx, 2));
    mx = fmaxf(mx, __shfl_xor(mx, 4));
    mx = fmaxf(mx, __shfl_xor(mx, 8));
    float sm = 0.f;
    #pragma unroll
    for (int j = 0; j < 32; ++j) { v[j] = __expf(v[j] - mx); sm += v[j]; }
    sm += __shfl_xor(sm, 1);
    sm += __shfl_xor(sm, 2);
    sm += __shfl_xor(sm, 4);
    sm += __shfl_xor(sm, 8);
    const float inv = 1.f / sm;
    #pragma unroll
    for (int j = 0; j < 32; ++j) v[j] *= inv;

    // ---- global softmax over all 8192
    float m2 = v[0];
    #pragma unroll
    for (int j = 1; j < 32; ++j) m2 = fmaxf(m2, v[j]);
    for (int off = 32; off; off >>= 1) m2 = fmaxf(m2, __shfl_xor(m2, off));
    if (lane == 0) redf[wv] = m2;
    __syncthreads();
    const float gm = fmaxf(fmaxf(redf[0], redf[1]), fmaxf(redf[2], redf[3]));
    __syncthreads();
    float s2 = 0.f;
    #pragma unroll
    for (int j = 0; j < 32; ++j) { v[j] = __expf(v[j] - gm); s2 += v[j]; }
    for (int off = 32; off; off >>= 1) s2 += __shfl_xor(s2, off);
    if (lane == 0) redf[wv] = s2;
    __syncthreads();
    const float gi = 1.f / (redf[0] + redf[1] + redf[2] + redf[3]);

    // ---- this block's 32 weights live in thread t == b
    if (t == b) {
        #pragma unroll
        for (int j = 0; j < 32; ++j) wloc[j] = v[j] * gi;
    }
    __syncthreads();

    // ---- weighted sum of rows [b*32, b*32+32)
    float a0 = 0.f, a1 = 0.f;
    #pragma unroll 4
    for (int j = 0; j < 32; ++j) {
        const float wj = wloc[j];
        const float* hr = h_full + (size_t)(b * 32 + j) * EMBED;
        a0 = fmaf(wj, hr[t], a0);
        a1 = fmaf(wj, hr[t + 256], a1);
    }
    atomicAdd(&svec[t], a0);
    atomicAdd(&svec[t + 256], a1);
}

// ============================================================
// 5) attn0 += svec @ Wv  (attn0 pre-seeded with bv)  grid 32 x 256
// ============================================================
__global__ void k_attn0(const float* __restrict__ svec, const float* __restrict__ Wv,
                        float* __restrict__ attn0) {
    const int b = blockIdx.x, t = threadIdx.x;
    float a0 = 0.f, a1 = 0.f;
    const int e0 = b * 16;
    for (int e = e0; e < e0 + 16; ++e) {
        const float s = svec[e];
        const float* wr = Wv + (size_t)e * EMBED;
        a0 = fmaf(s, wr[t], a0);
        a1 = fmaf(s, wr[t + 256], a1);
    }
    atomicAdd(&attn0[t], a0);
    atomicAdd(&attn0[t + 256], a1);
}

// ============================================================
// 6) r0 += attn0 @ Wo  (r0 pre-seeded with cls+bo)  grid 32 x 256
// ============================================================
__global__ void k_r0(const float* __restrict__ attn0, const float* __restrict__ Wo,
                     float* __restrict__ r0) {
    const int b = blockIdx.x, t = threadIdx.x;
    float a0 = 0.f, a1 = 0.f;
    const int e0 = b * 16;
    for (int e = e0; e < e0 + 16; ++e) {
        const float s = attn0[e];
        const float* wr = Wo + (size_t)e * EMBED;
        a0 = fmaf(s, wr[t], a0);
        a1 = fmaf(s, wr[t + 256], a1);
    }
    atomicAdd(&r0[t], a0);
    atomicAdd(&r0[t + 256], a1);
}

// ============================================================
// 7) LayerNorm(r0) -> logits = hn @ Wc + bc    1 block x 512
// ============================================================
__global__ void k_final(const float* __restrict__ r0, const float* __restrict__ ln_g,
                        const float* __restrict__ ln_b, const float* __restrict__ Wc,
                        const float* __restrict__ bc, float* __restrict__ out) {
    __shared__ float red[8];
    const int t = threadIdx.x, wv = t >> 6, lane = t & 63;
    const float x = r0[t];

    float sm = x;
    for (int off = 32; off; off >>= 1) sm += __shfl_down(sm, off);
    if (lane == 0) red[wv] = sm;
    __syncthreads();
    float mu = 0.f;
    for (int i = 0; i < 8; ++i) mu += red[i];
    mu *= (1.f / 512.f);
    const float dx = x - mu;

    __syncthreads();
    float q = dx * dx;
    for (int off = 32; off; off >>= 1) q += __shfl_down(q, off);
    if (lane == 0) red[wv] = q;
    __syncthreads();
    float var = 0.f;
    for (int i = 0; i < 8; ++i) var += red[i];
    var *= (1.f / 512.f);

    const float hn = dx / sqrtf(var + 1e-5f) * ln_g[t] + ln_b[t];
    float p0 = hn * Wc[2 * t];
    float p1 = hn * Wc[2 * t + 1];

    __syncthreads();
    for (int off = 32; off; off >>= 1) p0 += __shfl_down(p0, off);
    if (lane == 0) red[wv] = p0;
    __syncthreads();
    if (t == 0) {
        float tot = 0.f;
        for (int i = 0; i < 8; ++i) tot += red[i];
        out[0] = tot + bc[0];
    }
    __syncthreads();
    for (int off = 32; off; off >>= 1) p1 += __shfl_down(p1, off);
    if (lane == 0) red[wv] = p1;
    __syncthreads();
    if (t == 0) {
        float tot = 0.f;
        for (int i = 0; i < 8; ++i) tot += red[i];
        out[1] = tot + bc[1];
    }
}

// ============================================================
extern "C" void kernel_launch(void* const* d_in, const int* in_sizes, int n_in,
                              void* d_out, int out_size, void* d_ws, size_t ws_size,
                              hipStream_t stream) {
    const float* x    = (const float*)d_in[0];
    const float* W1   = (const float*)d_in[1];
    const float* b1   = (const float*)d_in[2];
    const float* cls  = (const float*)d_in[3];
    const float* Wq   = (const float*)d_in[4];
    const float* bq   = (const float*)d_in[5];
    const float* Wk   = (const float*)d_in[6];
    const float* bk   = (const float*)d_in[7];   (void)bk;  // uniform shift cancels in softmax
    const float* Wv   = (const float*)d_in[8];
    const float* bv   = (const float*)d_in[9];
    const float* Wo   = (const float*)d_in[10];
    const float* bo   = (const float*)d_in[11];
    const float* ln_g = (const float*)d_in[12];
    const float* ln_b = (const float*)d_in[13];
    const float* Wc   = (const float*)d_in[14];
    const float* bc   = (const float*)d_in[15];
    float* out = (float*)d_out;

    char* ws = (char*)d_ws;
    unsigned short* xb     = (unsigned short*)(ws);                    // 16 MB
    unsigned short* w1t    = (unsigned short*)(ws + 16777216);         // 1 MB
    float*          h_full = (float*)(ws + 17825792);                  // 16 MB
    float*          scores = (float*)(ws + 34603008);                  // 32 KB
    float*          q0     = (float*)(ws + 34668544);
    float*          u      = (float*)(ws + 34670592);
    float*          svec   = (float*)(ws + 34672640);
    float*          attn0  = (float*)(ws + 34674688);
    float*          r0     = (float*)(ws + 34676736);

    k_pre   <<<1544, 256, 0, stream>>>(x, xb, W1, w1t, cls, Wq, bq, bv, bo,
                                       q0, h_full, svec, attn0, r0, scores);
    k_u     <<<32,   256, 0, stream>>>(Wk, q0, u);
    k_gemm  <<<256,  256, 0, stream>>>(xb, w1t, b1, u, h_full, scores);
    k_wsum  <<<256,  256, 0, stream>>>(scores, h_full, u, cls, svec);
    k_attn0 <<<32,   256, 0, stream>>>(svec, Wv, attn0);
    k_r0    <<<32,   256, 0, stream>>>(attn0, Wo, r0);
    k_final <<<1,    512, 0, stream>>>(r0, ln_g, ln_b, Wc, bc, out);
}

// Round 8
// 159.485 us; speedup vs baseline: 1.1791x; 1.1605x over previous
//
#include <hip/hip_runtime.h>
#include <math.h>

// ---------- types ----------
typedef __attribute__((ext_vector_type(8))) short bf16x8;   // 8 x bf16
typedef __attribute__((ext_vector_type(4))) float f32x4;

#define AS1(p) ((__attribute__((address_space(1))) void*)(uintptr_t)(p))
#define AS3(p) ((__attribute__((address_space(3))) void*)(p))

static __device__ __forceinline__ unsigned short f2bf(float f) {
    unsigned int u = __float_as_uint(f);
    unsigned int r = (u + 0x7fffu + ((u >> 16) & 1u)) >> 16;   // RNE
    return (unsigned short)r;
}

// ---------- sizes ----------
#define NPATCH 8191
#define NTOK   8192          // with cls row 0
#define INDIM  1024
#define EMBED  512

// ============================================================
// 1) k_misc: blocks 0..31   q0 += cls[16b..16b+16) @ Wq rows (atomic,
//                           q0 pre-zeroed by memset; 32KB contiguous/block)
//            block  32      tiny inits (h row0, attn0=bv, r0=cls+bo)
//            blocks 33..544 W1 -> w1t [N][K] bf16 transpose
// ============================================================
__global__ void k_misc(const float* __restrict__ W1, unsigned short* __restrict__ w1t,
                       const float* __restrict__ cls, const float* __restrict__ Wq,
                       const float* __restrict__ bv, const float* __restrict__ bo,
                       float* __restrict__ q0, float* __restrict__ h_full,
                       float* __restrict__ attn0, float* __restrict__ r0) {
    const int b = blockIdx.x;
    const int t = threadIdx.x;
    if (b < 32) {
        // q0 partial: rows [16b, 16b+16), thread t owns cols t and t+256
        const float* wr = Wq + (size_t)(b * 16) * EMBED;
        float a0 = 0.f, a1 = 0.f;
        #pragma unroll
        for (int r = 0; r < 16; ++r) {
            const float c = cls[b * 16 + r];
            a0 = fmaf(c, wr[r * EMBED + t], a0);
            a1 = fmaf(c, wr[r * EMBED + t + 256], a1);
        }
        atomicAdd(&q0[t], a0);
        atomicAdd(&q0[t + 256], a1);
    } else if (b == 32) {
        const float c0 = cls[t], c1 = cls[t + 256];
        h_full[t]     = c0;       h_full[t + 256] = c1;
        attn0[t]      = bv[t];    attn0[t + 256]  = bv[t + 256];
        r0[t]         = c0 + bo[t];  r0[t + 256]  = c1 + bo[t + 256];
    } else {
        __shared__ float tile[32][33];
        const int bb = b - 33;
        const int bk = bb >> 4;              // 0..31 (K tiles)
        const int bn = bb & 15;              // 0..15 (N tiles)
        const int r  = t >> 3;               // 0..31
        const int c4 = (t & 7) * 4;          // 0,4,..,28
        float4 v = *(const float4*)(W1 + (size_t)(bk * 32 + r) * EMBED + bn * 32 + c4);
        tile[r][c4 + 0] = v.x; tile[r][c4 + 1] = v.y; tile[r][c4 + 2] = v.z; tile[r][c4 + 3] = v.w;
        __syncthreads();
        ushort4 o;
        o.x = f2bf(tile[c4 + 0][r]); o.y = f2bf(tile[c4 + 1][r]);
        o.z = f2bf(tile[c4 + 2][r]); o.w = f2bf(tile[c4 + 3][r]);
        *(ushort4*)(w1t + (size_t)(bn * 32 + r) * INDIM + bk * 32 + c4) = o;
    }
}

// ============================================================
// 2) k_conv: x (f32) -> xb (bf16), 8 indep float4 loads/thread
//    grid 1024 x 256
// ============================================================
__global__ void k_conv(const float* __restrict__ x, unsigned short* __restrict__ xb) {
    const int base = blockIdx.x * 2048 + threadIdx.x;   // float4 index
    const int NV   = NPATCH * INDIM / 4;                // 2,096,896 valid float4s
    const float4* x4 = (const float4*)x;
    ushort4* xb4 = (ushort4*)xb;
    float4 vv[8];
    #pragma unroll
    for (int k = 0; k < 8; ++k) {
        const int i = base + k * 256;
        if (i < NV) vv[k] = x4[i];
        else        vv[k] = make_float4(0.f, 0.f, 0.f, 0.f);
    }
    #pragma unroll
    for (int k = 0; k < 8; ++k) {
        ushort4 o;
        o.x = f2bf(vv[k].x); o.y = f2bf(vv[k].y);
        o.z = f2bf(vv[k].z); o.w = f2bf(vv[k].w);
        xb4[base + k * 256] = o;
    }
}

// ============================================================
// 3) u[in] = Wk[in,:] . (q0 + bq)   grid 32 x 256
// ============================================================
__global__ void k_u(const float* __restrict__ Wk, const float* __restrict__ q0,
                    const float* __restrict__ bq, float* __restrict__ u) {
    const int wave = blockIdx.x * 4 + (threadIdx.x >> 6);  // 0..127
    const int lane = threadIdx.x & 63;
    const float4* q4 = (const float4*)q0;
    const float4* b4 = (const float4*)bq;
    float4 qa = q4[lane * 2], qb = q4[lane * 2 + 1];
    float4 ba = b4[lane * 2], bb = b4[lane * 2 + 1];
    qa.x += ba.x; qa.y += ba.y; qa.z += ba.z; qa.w += ba.w;
    qb.x += bb.x; qb.y += bb.y; qb.z += bb.z; qb.w += bb.w;
    for (int rr = 0; rr < 4; ++rr) {
        const int row = wave * 4 + rr;                     // 0..511
        const float4* wr = (const float4*)(Wk + (size_t)row * EMBED);
        float4 a = wr[lane * 2], b = wr[lane * 2 + 1];
        float acc = a.x*qa.x + a.y*qa.y + a.z*qa.z + a.w*qa.w
                  + b.x*qb.x + b.y*qb.y + b.z*qb.z + b.w*qb.w;
        for (int off = 32; off; off >>= 1) acc += __shfl_down(acc, off);
        if (lane == 0) u[row] = acc;
    }
}

// ============================================================
// 4) GEMM: h_full[1+a][n] = relu( xb[a,:] @ w1t[n,:]^T + b1[n] )
//    + fused scores[1+a] = h_row . u  (raw dot, scaled later)
//    128x128 tile, BK=128, dbuf LDS (128KB), grid 256 (1 blk/CU)
//    Both operands via global_load_lds w=16, pre-swizzled source,
//    XOR-swizzled ds_read_b128 (conflict-free). 8-iter K chain.
// ============================================================
__global__ __launch_bounds__(256) void k_gemm(const unsigned short* __restrict__ xb,
                                              const unsigned short* __restrict__ w1t,
                                              const float* __restrict__ b1,
                                              const float* __restrict__ u,
                                              float* __restrict__ h_full,
                                              float* __restrict__ scores) {
    __shared__ __align__(16) unsigned short As[2][128 * 128];   // 32 KB x2
    __shared__ __align__(16) unsigned short Bs[2][128 * 128];   // 32 KB x2
    const int tid  = threadIdx.x;
    const int wave = tid >> 6;
    const int lane = tid & 63;
    const int bid  = blockIdx.x;
    const int rg   = (bid & 7) | ((bid >> 5) << 3);   // 0..63
    const int cg   = (bid >> 3) & 3;                  // 0..3
    const int wr   = wave >> 1, wc = wave & 1;
    const int fr   = lane & 15, fq = lane >> 4;

    size_t srcA[8], srcB[8];
    int dstc[8];
    #pragma unroll
    for (int i = 0; i < 8; ++i) {
        const int c0  = (i * 4 + wave) * 64;          // wave-uniform
        const int c   = c0 + lane;
        const int row = c >> 4, koct = c & 15;
        const int kg  = koct ^ (row & 7);
        dstc[i] = c0 * 8;                             // shorts
        srcA[i] = (size_t)(rg * 128 + row) * INDIM + kg * 8;
        srcB[i] = (size_t)(cg * 128 + row) * INDIM + kg * 8;
    }

    f32x4 acc[4][4] = {};

    int aoff[4], boff[4];
    #pragma unroll
    for (int mi = 0; mi < 4; ++mi) {
        const int row = wr * 64 + mi * 16 + fr;
        aoff[mi] = row * 128 + ((fq ^ (row & 7)) * 8);
        const int col = wc * 64 + mi * 16 + fr;
        boff[mi] = col * 128 + ((fq ^ (col & 7)) * 8);
    }

#define STAGE(buf, k0) do { \
    _Pragma("unroll") \
    for (int i = 0; i < 8; ++i) \
        __builtin_amdgcn_global_load_lds(AS1(xb + srcA[i] + (k0)), \
                                         AS3(&As[buf][dstc[i]]), 16, 0, 0); \
    _Pragma("unroll") \
    for (int i = 0; i < 8; ++i) \
        __builtin_amdgcn_global_load_lds(AS1(w1t + srcB[i] + (k0)), \
                                         AS3(&Bs[buf][dstc[i]]), 16, 0, 0); \
    } while (0)

    STAGE(0, 0);
    __syncthreads();

    int cur = 0;
    for (int kt = 0; kt < 8; ++kt) {
        if (kt < 7) STAGE(cur ^ 1, (kt + 1) * 128);   // prefetch overlaps compute
        #pragma unroll
        for (int kk = 0; kk < 4; ++kk) {
            bf16x8 af[4], bf[4];
            #pragma unroll
            for (int mi = 0; mi < 4; ++mi)
                af[mi] = *(const bf16x8*)&As[cur][aoff[mi] ^ (kk * 32)];
            #pragma unroll
            for (int ni = 0; ni < 4; ++ni)
                bf[ni] = *(const bf16x8*)&Bs[cur][boff[ni] ^ (kk * 32)];
            #pragma unroll
            for (int mi = 0; mi < 4; ++mi)
                #pragma unroll
                for (int ni = 0; ni < 4; ++ni)
                    acc[mi][ni] = __builtin_amdgcn_mfma_f32_16x16x32_bf16(af[mi], bf[ni], acc[mi][ni], 0, 0, 0);
        }
        __syncthreads();
        cur ^= 1;
    }
#undef STAGE

    float uv[4], bvv[4];
    #pragma unroll
    for (int ni = 0; ni < 4; ++ni) {
        const int col = cg * 128 + wc * 64 + ni * 16 + fr;
        uv[ni]  = u[col];
        bvv[ni] = b1[col];
    }
    #pragma unroll
    for (int mi = 0; mi < 4; ++mi) {
        #pragma unroll
        for (int rr = 0; rr < 4; ++rr) {
            const int a = rg * 128 + wr * 64 + mi * 16 + fq * 4 + rr;
            if (a < NPATCH) {
                float sc = 0.f;
                #pragma unroll
                for (int ni = 0; ni < 4; ++ni) {
                    const int col = cg * 128 + wc * 64 + ni * 16 + fr;
                    float v = fmaxf(acc[mi][ni][rr] + bvv[ni], 0.f);
                    h_full[(size_t)(a + 1) * EMBED + col] = v;
                    sc = fmaf(v, uv[ni], sc);
                }
                sc += __shfl_xor(sc, 1);
                sc += __shfl_xor(sc, 2);
                sc += __shfl_xor(sc, 4);
                sc += __shfl_xor(sc, 8);
                if (fr == 0) atomicAdd(&scores[a + 1], sc);
            }
        }
    }
}

// ============================================================
// 5) FUSED softmax + wsum.  grid 256 x 256.
//    Each block redundantly computes the full two-stage softmax
//    (thread t owns scores[32t..32t+32); chunk = 16-lane group),
//    then does the weighted h-row sum for its own 32 rows.
// ============================================================
__global__ void k_wsum(const float* __restrict__ scores, const float* __restrict__ h_full,
                       const float* __restrict__ u, const float* __restrict__ cls,
                       float* __restrict__ svec) {
    __shared__ float redf[4];
    __shared__ float wloc[32];
    const int b = blockIdx.x, t = threadIdx.x;
    const int wv = t >> 6, lane = t & 63;
    const float rs = 0.04419417382415922f;   // 1/sqrt(512)

    // ---- s0 = (cls . u) * rs
    float part = cls[t] * u[t] + cls[t + 256] * u[t + 256];
    for (int off = 32; off; off >>= 1) part += __shfl_down(part, off);
    if (lane == 0) redf[wv] = part;
    __syncthreads();
    const float s0 = (redf[0] + redf[1] + redf[2] + redf[3]) * rs;
    __syncthreads();   // all reads of redf done before reuse

    // ---- load 32 scores (thread t owns j in [32t, 32t+32))
    float v[32];
    const float4* s4 = (const float4*)(scores + t * 32);
    #pragma unroll
    for (int q = 0; q < 8; ++q) {
        float4 a = s4[q];
        v[q*4+0] = a.x*rs; v[q*4+1] = a.y*rs; v[q*4+2] = a.z*rs; v[q*4+3] = a.w*rs;
    }
    if (t == 0) v[0] = s0;

    // ---- chunk softmax: chunk = 16-lane group (512 scores)
    float mx = v[0];
    #pragma unroll
    for (int j = 1; j < 32; ++j) mx = fmaxf(mx, v[j]);
    mx = fmaxf(mx, __shfl_xor(mx, 1));
    mx = fmaxf(mx, __shfl_xor(mx, 2));
    mx = fmaxf(mx, __shfl_xor(mx, 4));
    mx = fmaxf(mx, __shfl_xor(mx, 8));
    float sm = 0.f;
    #pragma unroll
    for (int j = 0; j < 32; ++j) { v[j] = __expf(v[j] - mx); sm += v[j]; }
    sm += __shfl_xor(sm, 1);
    sm += __shfl_xor(sm, 2);
    sm += __shfl_xor(sm, 4);
    sm += __shfl_xor(sm, 8);
    const float inv = 1.f / sm;
    #pragma unroll
    for (int j = 0; j < 32; ++j) v[j] *= inv;

    // ---- global softmax over all 8192
    float m2 = v[0];
    #pragma unroll
    for (int j = 1; j < 32; ++j) m2 = fmaxf(m2, v[j]);
    for (int off = 32; off; off >>= 1) m2 = fmaxf(m2, __shfl_xor(m2, off));
    if (lane == 0) redf[wv] = m2;
    __syncthreads();
    const float gm = fmaxf(fmaxf(redf[0], redf[1]), fmaxf(redf[2], redf[3]));
    __syncthreads();
    float s2 = 0.f;
    #pragma unroll
    for (int j = 0; j < 32; ++j) { v[j] = __expf(v[j] - gm); s2 += v[j]; }
    for (int off = 32; off; off >>= 1) s2 += __shfl_xor(s2, off);
    if (lane == 0) redf[wv] = s2;
    __syncthreads();
    const float gi = 1.f / (redf[0] + redf[1] + redf[2] + redf[3]);

    // ---- this block's 32 weights live in thread t == b
    if (t == b) {
        #pragma unroll
        for (int j = 0; j < 32; ++j) wloc[j] = v[j] * gi;
    }
    __syncthreads();

    // ---- weighted sum of rows [b*32, b*32+32)
    float a0 = 0.f, a1 = 0.f;
    #pragma unroll 4
    for (int j = 0; j < 32; ++j) {
        const float wj = wloc[j];
        const float* hr = h_full + (size_t)(b * 32 + j) * EMBED;
        a0 = fmaf(wj, hr[t], a0);
        a1 = fmaf(wj, hr[t + 256], a1);
    }
    atomicAdd(&svec[t], a0);
    atomicAdd(&svec[t + 256], a1);
}

// ============================================================
// 6) attn0 += svec @ Wv  (attn0 pre-seeded with bv)  grid 32 x 256
// ============================================================
__global__ void k_attn0(const float* __restrict__ svec, const float* __restrict__ Wv,
                        float* __restrict__ attn0) {
    const int b = blockIdx.x, t = threadIdx.x;
    float a0 = 0.f, a1 = 0.f;
    const int e0 = b * 16;
    #pragma unroll
    for (int e = e0; e < e0 + 16; ++e) {
        const float s = svec[e];
        const float* wr = Wv + (size_t)e * EMBED;
        a0 = fmaf(s, wr[t], a0);
        a1 = fmaf(s, wr[t + 256], a1);
    }
    atomicAdd(&attn0[t], a0);
    atomicAdd(&attn0[t + 256], a1);
}

// ============================================================
// 7) r0 += attn0 @ Wo  (r0 pre-seeded with cls+bo)  grid 32 x 256
// ============================================================
__global__ void k_r0(const float* __restrict__ attn0, const float* __restrict__ Wo,
                     float* __restrict__ r0) {
    const int b = blockIdx.x, t = threadIdx.x;
    float a0 = 0.f, a1 = 0.f;
    const int e0 = b * 16;
    #pragma unroll
    for (int e = e0; e < e0 + 16; ++e) {
        const float s = attn0[e];
        const float* wr = Wo + (size_t)e * EMBED;
        a0 = fmaf(s, wr[t], a0);
        a1 = fmaf(s, wr[t + 256], a1);
    }
    atomicAdd(&r0[t], a0);
    atomicAdd(&r0[t + 256], a1);
}

// ============================================================
// 8) LayerNorm(r0) -> logits = hn @ Wc + bc    1 block x 512
// ============================================================
__global__ void k_final(const float* __restrict__ r0, const float* __restrict__ ln_g,
                        const float* __restrict__ ln_b, const float* __restrict__ Wc,
                        const float* __restrict__ bc, float* __restrict__ out) {
    __shared__ float red[8];
    const int t = threadIdx.x, wv = t >> 6, lane = t & 63;
    const float x = r0[t];

    float sm = x;
    for (int off = 32; off; off >>= 1) sm += __shfl_down(sm, off);
    if (lane == 0) red[wv] = sm;
    __syncthreads();
    float mu = 0.f;
    for (int i = 0; i < 8; ++i) mu += red[i];
    mu *= (1.f / 512.f);
    const float dx = x - mu;

    __syncthreads();
    float q = dx * dx;
    for (int off = 32; off; off >>= 1) q += __shfl_down(q, off);
    if (lane == 0) red[wv] = q;
    __syncthreads();
    float var = 0.f;
    for (int i = 0; i < 8; ++i) var += red[i];
    var *= (1.f / 512.f);

    const float hn = dx / sqrtf(var + 1e-5f) * ln_g[t] + ln_b[t];
    float p0 = hn * Wc[2 * t];
    float p1 = hn * Wc[2 * t + 1];

    __syncthreads();
    for (int off = 32; off; off >>= 1) p0 += __shfl_down(p0, off);
    if (lane == 0) red[wv] = p0;
    __syncthreads();
    if (t == 0) {
        float tot = 0.f;
        for (int i = 0; i < 8; ++i) tot += red[i];
        out[0] = tot + bc[0];
    }
    __syncthreads();
    for (int off = 32; off; off >>= 1) p1 += __shfl_down(p1, off);
    if (lane == 0) red[wv] = p1;
    __syncthreads();
    if (t == 0) {
        float tot = 0.f;
        for (int i = 0; i < 8; ++i) tot += red[i];
        out[1] = tot + bc[1];
    }
}

// ============================================================
extern "C" void kernel_launch(void* const* d_in, const int* in_sizes, int n_in,
                              void* d_out, int out_size, void* d_ws, size_t ws_size,
                              hipStream_t stream) {
    const float* x    = (const float*)d_in[0];
    const float* W1   = (const float*)d_in[1];
    const float* b1   = (const float*)d_in[2];
    const float* cls  = (const float*)d_in[3];
    const float* Wq   = (const float*)d_in[4];
    const float* bq   = (const float*)d_in[5];
    const float* Wk   = (const float*)d_in[6];
    const float* bk   = (const float*)d_in[7];   (void)bk;  // uniform shift cancels in softmax
    const float* Wv   = (const float*)d_in[8];
    const float* bv   = (const float*)d_in[9];
    const float* Wo   = (const float*)d_in[10];
    const float* bo   = (const float*)d_in[11];
    const float* ln_g = (const float*)d_in[12];
    const float* ln_b = (const float*)d_in[13];
    const float* Wc   = (const float*)d_in[14];
    const float* bc   = (const float*)d_in[15];
    float* out = (float*)d_out;

    char* ws = (char*)d_ws;
    unsigned short* xb     = (unsigned short*)(ws);                    // 16 MB
    unsigned short* w1t    = (unsigned short*)(ws + 16777216);         // 1 MB
    float*          h_full = (float*)(ws + 17825792);                  // 16 MB
    // contiguous zero-init region: scores[8192], q0[512], svec[512]
    float*          scores = (float*)(ws + 34603008);                  // 32 KB
    float*          q0     = (float*)(ws + 34635776);                  // 2 KB
    float*          svec   = (float*)(ws + 34637824);                  // 2 KB
    float*          attn0  = (float*)(ws + 34639872);
    float*          r0     = (float*)(ws + 34641920);
    float*          u      = (float*)(ws + 34643968);

    hipMemsetAsync(scores, 0, (8192 + 512 + 512) * sizeof(float), stream);
    k_misc  <<<545,  256, 0, stream>>>(W1, w1t, cls, Wq, bv, bo, q0, h_full, attn0, r0);
    k_conv  <<<1024, 256, 0, stream>>>(x, xb);
    k_u     <<<32,   256, 0, stream>>>(Wk, q0, bq, u);
    k_gemm  <<<256,  256, 0, stream>>>(xb, w1t, b1, u, h_full, scores);
    k_wsum  <<<256,  256, 0, stream>>>(scores, h_full, u, cls, svec);
    k_attn0 <<<32,   256, 0, stream>>>(svec, Wv, attn0);
    k_r0    <<<32,   256, 0, stream>>>(attn0, Wo, r0);
    k_final <<<1,    512, 0, stream>>>(r0, ln_g, ln_b, Wc, bc, out);
}